// Round 9
// baseline (364.074 us; speedup 1.0000x reference)
//
#include <hip/hip_runtime.h>
#include <hip/hip_bf16.h>

typedef unsigned short u16;
typedef __attribute__((ext_vector_type(4))) unsigned short u16x4;
typedef __attribute__((ext_vector_type(8))) unsigned short u16x8;
typedef __attribute__((ext_vector_type(8))) __bf16 bf16x8;
typedef __attribute__((ext_vector_type(4))) float f32x4;

#define BB 16
#define TSEQ 1024
#define CC 584          /* embed dim */
#define HH 8
#define DHD 73
#define NR (BB*TSEQ)    /* 16384 rows */
#define KPW 640         /* padded K: 10 x 64 K-tiles */
#define DP 80           /* padded head dim (73 -> 80 = 5x16) */
#define HD (HH*DP)      /* 640 */
#define NP3 768         /* padded N for final proj */
#define PPITCH 72       /* Pt pitch: 64 cols + 8 pad (16B aligned, 2-way banks) */
/* exp(s*584^-0.5) == exp2(s * CEXP); scores bounded -> no max subtraction */
#define CEXP 0.0596985934f

__device__ __forceinline__ u16 f2bf(float f) {
  __bf16 h = (__bf16)f;                 // native v_cvt, RNE
  return __builtin_bit_cast(u16, h);
}
__device__ __forceinline__ bf16x8 as_bf(u16x8 v) { return __builtin_bit_cast(bf16x8, v); }

/* async global->LDS, 16B/lane, LDS dst = wave-uniform base + lane*16 */
#define GLL16(g, l) __builtin_amdgcn_global_load_lds( \
    (const __attribute__((address_space(1))) void*)(g), \
    (__attribute__((address_space(3))) void*)(l), 16, 0, 0)

#define BARRIER() asm volatile("s_barrier" ::: "memory")
#define VMW8()    asm volatile("s_waitcnt vmcnt(8)" ::: "memory")
#define VMW0()    asm volatile("s_waitcnt vmcnt(0)" ::: "memory")

// ---------------- fused pack kernel (r7 config, kept) ----------------
#define PKA2 1280
#define PKB2 600
#define PKC2 240
__global__ void pack_all_kernel(const float* __restrict__ x, const float* __restrict__ mem,
                                const float* __restrict__ Wq, const float* __restrict__ Wk,
                                const float* __restrict__ Wv, const float* __restrict__ Wp,
                                u16* __restrict__ xmb, u16* __restrict__ wt,
                                u16* __restrict__ wpt) {
  const int bidx = blockIdx.x;
  const int tid = threadIdx.x;
  if (bidx < PKA2) {
    const int base = bidx * 2048 + tid;
#pragma unroll
    for (int e = 0; e < 8; e++) {
      int idx = base + e * 256;
      int row = idx / (KPW / 8);
      int c8  = (idx % (KPW / 8)) * 8;
      u16x8 o = {0, 0, 0, 0, 0, 0, 0, 0};
      if (c8 < CC) {
        const float* src = (row < NR) ? &x[(size_t)row * CC + c8]
                                      : &mem[(size_t)(row - NR) * CC + c8];
        f32x4 a = *(const f32x4*)src;
        f32x4 b = *(const f32x4*)(src + 4);
#pragma unroll
        for (int t = 0; t < 4; t++) { o[t] = f2bf(a[t]); o[4 + t] = f2bf(b[t]); }
      }
      *(u16x8*)&xmb[(size_t)row * KPW + c8] = o;
    }
  } else if (bidx < PKA2 + PKB2) {
    const int base = (bidx - PKA2) * 2048 + tid;
#pragma unroll
    for (int e = 0; e < 8; e++) {
      int idx = base + e * 256;
      int w   = idx / (HD * KPW);
      int rem = idx % (HD * KPW);
      int n = rem / KPW;
      int k = rem % KPW;
      int h = n / DP, d = n % DP;
      u16 val = 0;
      if (d < DHD && k < CC) {
        const float* W = (w == 0) ? Wq : ((w == 1) ? Wv : Wk);  // order: q, v, k
        val = f2bf(W[((size_t)h * CC + k) * DHD + d]);
      }
      wt[idx] = val;
    }
  } else {
    const int base = (bidx - PKA2 - PKB2) * 2048 + tid;
#pragma unroll
    for (int e = 0; e < 8; e++) {
      int idx = base + e * 256;
      int n = idx / KPW;
      int c = idx % KPW;
      u16 val = 0;
      if (n < CC && c < CC) val = f2bf(Wp[(size_t)c * CC + n]);
      wpt[idx] = val;
    }
  }
}

// ---------------- 128x128 GEMM, BK=64 dbuf, 2 blocks/CU (r8 proven) ----------------
__device__ __forceinline__ void rd4(bf16x8 (&v)[4][2], const u16* lds, int base,
                                    int sw0, int sw1) {
#pragma unroll
  for (int q = 0; q < 4; q++) {
    const int r = base + q * 1024;
    v[q][0] = as_bf(*(const u16x8*)&lds[r + sw0]);
    v[q][1] = as_bf(*(const u16x8*)&lds[r + sw1]);
  }
}
__device__ __forceinline__ void stg128(const u16* gA, const u16* gB, u16* ldst, int t) {
  const int lb = (t & 1) * 8192;
  const size_t ko = (size_t)t * 64;
#pragma unroll
  for (int u = 0; u < 4; u++)
    GLL16(gA + (size_t)(u * 32) * KPW + ko, ldst + lb + u * 2048);
#pragma unroll
  for (int u = 0; u < 4; u++)
    GLL16(gB + (size_t)(u * 32) * KPW + ko, ldst + 16384 + lb + u * 2048);
}

template <int MODE>
__global__ __launch_bounds__(256, 2) void gemm8_kernel(
    const u16* __restrict__ A, const u16* __restrict__ Bt,
    void* __restrict__ CoutV, void* __restrict__ CoutV2,
    const float* __restrict__ bias) {
  extern __shared__ u16 lds[];
  const int tid  = threadIdx.x;
  const int lane = tid & 63;
  const int q15  = lane & 15;
  const int quad = lane >> 4;
  const int wave = tid >> 6;      // 0..3
  const int wmi  = wave >> 1;     // 0..1
  const int wni  = wave & 1;      // 0..1

  // XCD-contiguous swizzle (grid % 8 == 0 for both modes)
  const int cpx = gridDim.x >> 3;
  const int bid = (blockIdx.x & 7) * cpx + (blockIdx.x >> 3);

  int m0, n0, npart;  // npart: 0=q 1=v 2=k (MODE4)
  if (MODE == 4) {
    if (bid < 1280) {
      m0 = (bid / 10) * 128; int nt = bid % 10;
      if (nt < 5) { n0 = nt * 128; npart = 0; }
      else        { n0 = 640 + (nt - 5) * 128; npart = 1; }
    } else {
      int b2 = bid - 1280;
      m0 = NR + (b2 / 5) * 128; n0 = 1280 + (b2 % 5) * 128; npart = 2;
    }
  } else {
    m0 = (bid / 6) * 128; n0 = (bid % 6) * 128; npart = 0;
  }

  // staging: thread t covers (row = t>>3 in a 32-row unit, chunk = t&7);
  // source chunk pre-swizzled so swizzled ds_read finds linear data (rule 21).
  const int tr   = tid >> 3;
  const int scol = ((tid & 7) ^ (tr & 7)) * 8;
  const u16* gA = &A[(size_t)(m0 + tr) * KPW + scol];
  const u16* gB = &Bt[(size_t)(n0 + tr) * KPW + scol];
  u16* ldst = &lds[tid * 8];

  // fragment-read swizzled 16B-slot offsets (frag row & 7 == q15 & 7)
  const int rb  = q15 & 7;
  const int sw0 = (quad ^ rb) * 8;
  const int sw1 = ((quad + 4) ^ rb) * 8;
  const int arow = (wmi * 64 + q15) * 64;
  const int brow = (wni * 64 + q15) * 64;

  f32x4 acc[4][4];
#pragma unroll
  for (int i = 0; i < 4; i++)
#pragma unroll
    for (int j = 0; j < 4; j++) acc[i][j] = (f32x4){0.f, 0.f, 0.f, 0.f};

  // prologue: tiles 0 and 1 staged; VMW8 -> tile 0 landed
  stg128(gA, gB, ldst, 0);
  stg128(gA, gB, ldst, 1);
  VMW8(); BARRIER();

#pragma unroll 1
  for (int t = 0; t < 10; ++t) {
    const int lb = (t & 1) * 8192;
    bf16x8 a[4][2], b[4][2];
    rd4(a, lds, lb + arow, sw0, sw1);
    rd4(b, lds, 16384 + lb + brow, sw0, sw1);
    __builtin_amdgcn_s_setprio(1);
#pragma unroll
    for (int mq = 0; mq < 4; mq++)
#pragma unroll
      for (int nq = 0; nq < 4; nq++) {
        f32x4 c = acc[mq][nq];
        c = __builtin_amdgcn_mfma_f32_16x16x32_bf16(a[mq][0], b[nq][0], c, 0, 0, 0);
        c = __builtin_amdgcn_mfma_f32_16x16x32_bf16(a[mq][1], b[nq][1], c, 0, 0, 0);
        acc[mq][nq] = c;
      }
    __builtin_amdgcn_s_setprio(0);
    if (t == 9) break;
    BARRIER();                       // all waves done reading buf(t)
    if (t < 8) { stg128(gA, gB, ldst, t + 2); VMW8(); }
    else       { VMW0(); }
    BARRIER();                       // tile t+1 visible
  }

  // epilogue: row = m0 + wmi*64 + mq*16 + quad*4 + r ; col = n0 + wni*64 + nq*16 + q15
  const int rowb = m0 + wmi * 64 + quad * 4;
  const int colb = n0 + wni * 64 + q15;
#pragma unroll
  for (int mq = 0; mq < 4; mq++)
#pragma unroll
    for (int nq = 0; nq < 4; nq++) {
      const f32x4 av = acc[mq][nq];
      const int row = rowb + mq * 16;
      const int col = colb + nq * 16;
      if (MODE == 4) {
        if (npart == 2) {          // k projection -> k_buf
          u16* Cout = (u16*)CoutV2;
          const int rk = row - NR;
          const int ck = col - 1280;
#pragma unroll
          for (int r = 0; r < 4; r++)
            Cout[(size_t)(rk + r) * HD + ck] = f2bf(av[r]);
        } else if (npart == 0) {   // q projection, row-major
          u16* Cout = (u16*)CoutV;
#pragma unroll
          for (int r = 0; r < 4; r++)
            Cout[(size_t)(row + r) * HD + col] = f2bf(av[r]);
        } else {                   // v projection, transposed store
          u16* Cout = (u16*)CoutV;
          const int vn = col - 640;
          const int bb = row >> 10;
          const int tl = row & 1023;
          u16x4 pk;
#pragma unroll
          for (int r = 0; r < 4; r++) pk[r] = f2bf(av[r]);
          *(u16x4*)&Cout[(size_t)(NR * HD) + ((size_t)(bb * HD + vn)) * TSEQ + tl] = pk;
        }
      } else {
        if (col < CC) {
          float* Cout = (float*)CoutV;
          const float bvv = bias[col];
#pragma unroll
          for (int r = 0; r < 4; r++)
            Cout[(size_t)(row + r) * CC + col] = av[r] + bvv;
        }
      }
    }
}

// ---------------- flash attention: 40KB LDS -> 4 blocks/CU, grid co-resident ----
// Pt pitch 88->72 (rows are 64 wide; 2-way banks kept). Ks [64][88]->[64][80]
// with chunk-XOR swizzle on chunks 0..7 (reg-staged: swizzle BOTH ds_write and
// ds_read — rule 21 both-sides); chunks 8,9 (k 64..79 tail) unswizzled
// (verified 4-lane/window = b128 minimum on the 32-active-lane tail read).
// LDS = 9216 + 5120 + 5760 u16 = 40192 B <= 40960 -> 4 blocks/CU; the
// 1024-block grid is exactly co-resident (4 x 256 CUs), no round tail.
__global__ __launch_bounds__(256, 4) void attn_kernel(
    const u16* __restrict__ qb, const u16* __restrict__ kb,
    const u16* __restrict__ vt, u16* __restrict__ attn) {
  __shared__ u16 smem[9216 + 5120 + 5760];
  u16* Pt = smem;                       // 4 waves x [32 q][72]
  u16* Ks = smem + 9216;                // [64 s][80] chunk-swizzled
  u16* Vs = smem + 9216 + 5120;         // [80 d][72] (64 s cols used)

  const int tid  = threadIdx.x;
  const int lane = tid & 63;
  const int wave = tid >> 6;
  const int q15  = lane & 15;
  const int quad = lane >> 4;
  const int bid  = blockIdx.x;
  const int loc  = bid >> 3;
  const int pair = (bid & 7) * 16 + (loc >> 3);
  const int b  = pair >> 3;
  const int h  = pair & 7;
  const int t0 = (loc & 7) * 128;
  const int wq0 = wave * 32;
  const bool w3 = (tid < 128);          // waves 0,1 handle the 3rd chunk

  // staging geometry: K = 64 rows x 10 chunks; V = 80 rows x 8 chunks (640 each)
  // K LDS offset swizzled: chunk c<8 -> c ^ (row&7); c in {8,9} unswizzled.
  int kgo[3], kso[3], vrow[3], vc[3];
#pragma unroll
  for (int p = 0; p < 3; p++) {
    int qk = tid + 256 * p;
    int kr = qk / 10, c = qk % 10;
    kgo[p] = kr * HD + c * 8;
    int cs = (c < 8) ? (c ^ (kr & 7)) : c;
    kso[p] = kr * 80 + cs * 8;
    vrow[p] = qk >> 3; vc[p] = (qk & 7) * 8;
  }
  const u16* kbase = &kb[(size_t)(b * TSEQ) * HD + h * DP];
  const u16* vbase = &vt[(size_t)(b * HD + h * DP) * TSEQ];

  // Q fragments direct from global (B-operand of S^T); tail quads>=2 zeroed
  bf16x8 aq[2][2], aqt[2];
  {
    const u16x8 z = {0, 0, 0, 0, 0, 0, 0, 0};
#pragma unroll
    for (int n = 0; n < 2; n++) {
      const size_t qrow = (size_t)(b * TSEQ + t0 + wq0 + n * 16 + q15) * HD + h * DP;
#pragma unroll
      for (int kcx = 0; kcx < 2; kcx++)
        aq[n][kcx] = as_bf(*(const u16x8*)&qb[qrow + kcx * 32 + quad * 8]);
      u16x8 tload = z;
      if (quad < 2) tload = *(const u16x8*)&qb[qrow + 64 + quad * 8];
      aqt[n] = as_bf(tload);
    }
  }

  // zero pad cols 584..639 of this block's output rows
  if (tid < 128) {
    const u16x8 z = {0, 0, 0, 0, 0, 0, 0, 0};
    size_t base = (size_t)(b * TSEQ + t0 + tid) * KPW + CC;
#pragma unroll
    for (int c = 0; c < (KPW - CC) / 8; c++) *(u16x8*)&attn[base + c * 8] = z;
  }

  float lsum[2] = {0.f, 0.f};
  f32x4 oacc[2][5];
#pragma unroll
  for (int m = 0; m < 2; m++)
#pragma unroll
    for (int jd = 0; jd < 5; jd++) oacc[m][jd] = (f32x4){0.f, 0.f, 0.f, 0.f};

  u16* Ptw = &Pt[wave * 32 * PPITCH];
  const int rb = q15 & 7;               // K-read swizzle row bits

  u16x8 kreg[3], vreg[3];
#pragma unroll
  for (int p = 0; p < 2; p++) {
    kreg[p] = *(const u16x8*)&kbase[kgo[p]];
    vreg[p] = *(const u16x8*)&vbase[(size_t)vrow[p] * TSEQ + vc[p]];
  }
  if (w3) {
    kreg[2] = *(const u16x8*)&kbase[kgo[2]];
    vreg[2] = *(const u16x8*)&vbase[(size_t)vrow[2] * TSEQ + vc[2]];
  }

  for (int si = 0; si < 16; ++si) {
#pragma unroll
    for (int p = 0; p < 2; p++) {
      *(u16x8*)&Ks[kso[p]] = kreg[p];
      *(u16x8*)&Vs[vrow[p] * 72 + vc[p]] = vreg[p];
    }
    if (w3) {
      *(u16x8*)&Ks[kso[2]] = kreg[2];
      *(u16x8*)&Vs[vrow[2] * 72 + vc[2]] = vreg[2];
    }
    __syncthreads();

    if (si < 15) {
      const int s1 = (si + 1) * 64;
#pragma unroll
      for (int p = 0; p < 2; p++) {
        kreg[p] = *(const u16x8*)&kbase[(size_t)s1 * HD + kgo[p]];
        vreg[p] = *(const u16x8*)&vbase[(size_t)vrow[p] * TSEQ + s1 + vc[p]];
      }
      if (w3) {
        kreg[2] = *(const u16x8*)&kbase[(size_t)s1 * HD + kgo[2]];
        vreg[2] = *(const u16x8*)&vbase[(size_t)vrow[2] * TSEQ + s1 + vc[2]];
      }
    }

    // S^T = K Q^T : rows = s (4 tiles), cols = q (2 tiles)
    f32x4 st[4][2];
#pragma unroll
    for (int mt = 0; mt < 4; mt++)
#pragma unroll
      for (int n = 0; n < 2; n++) st[mt][n] = (f32x4){0.f, 0.f, 0.f, 0.f};
#pragma unroll
    for (int kcx = 0; kcx < 2; kcx++) {
      bf16x8 ak[4];
#pragma unroll
      for (int mt = 0; mt < 4; mt++)
        ak[mt] = as_bf(*(const u16x8*)&Ks[(mt * 16 + q15) * 80 +
                                          ((kcx * 4 + quad) ^ rb) * 8]);
#pragma unroll
      for (int mt = 0; mt < 4; mt++)
#pragma unroll
        for (int n = 0; n < 2; n++)
          st[mt][n] = __builtin_amdgcn_mfma_f32_16x16x32_bf16(ak[mt], aq[n][kcx], st[mt][n], 0, 0, 0);
    }
    {  // tail: k 64..79 (chunks 8,9 unswizzled; quads >=2 zeroed on both operands)
      const u16x8 z = {0, 0, 0, 0, 0, 0, 0, 0};
#pragma unroll
      for (int mt = 0; mt < 4; mt++) {
        u16x8 tl = z;
        if (quad < 2) tl = *(const u16x8*)&Ks[(mt * 16 + q15) * 80 + 64 + quad * 8];
        bf16x8 akt = as_bf(tl);
#pragma unroll
        for (int n = 0; n < 2; n++)
          st[mt][n] = __builtin_amdgcn_mfma_f32_16x16x32_bf16(akt, aqt[n], st[mt][n], 0, 0, 0);
      }
    }

    // p = exp2(s*CEXP); per-lane partial row sums; vectorized Pt store (wave-private)
#pragma unroll
    for (int mt = 0; mt < 4; mt++)
#pragma unroll
      for (int n = 0; n < 2; n++) {
        f32x4 pv;
#pragma unroll
        for (int r = 0; r < 4; r++) pv[r] = __builtin_amdgcn_exp2f(st[mt][n][r] * CEXP);
        lsum[n] += (pv[0] + pv[1]) + (pv[2] + pv[3]);
        u16x4 pk;
#pragma unroll
        for (int r = 0; r < 4; r++) pk[r] = f2bf(pv[r]);
        *(u16x4*)&Ptw[(n * 16 + q15) * PPITCH + mt * 16 + quad * 4] = pk;
      }

    // O += P V  (A = P from Pt, b128 reads; B = V^T rows)
#pragma unroll
    for (int kcx = 0; kcx < 2; kcx++) {
      bf16x8 ap[2];
#pragma unroll
      for (int m = 0; m < 2; m++)
        ap[m] = as_bf(*(const u16x8*)&Ptw[(m * 16 + q15) * PPITCH + kcx * 32 + quad * 8]);
#pragma unroll
      for (int jd = 0; jd < 5; jd++) {
        bf16x8 bv = as_bf(*(const u16x8*)&Vs[(jd * 16 + q15) * 72 + kcx * 32 + quad * 8]);
#pragma unroll
        for (int m = 0; m < 2; m++)
          oacc[m][jd] = __builtin_amdgcn_mfma_f32_16x16x32_bf16(ap[m], bv, oacc[m][jd], 0, 0, 0);
      }
    }
    __syncthreads();
  }

  float lr[2];
#pragma unroll
  for (int n = 0; n < 2; n++) {
    float s = lsum[n];
    s += __shfl_xor(s, 16);
    s += __shfl_xor(s, 32);
    lr[n] = s;
  }

#pragma unroll
  for (int m = 0; m < 2; m++) {
#pragma unroll
    for (int r = 0; r < 4; r++) {
      const float inv = 1.f / __shfl(lr[m], quad * 4 + r);
      const int trow = t0 + wq0 + m * 16 + quad * 4 + r;
#pragma unroll
      for (int jd = 0; jd < 5; jd++) {
        const int d = jd * 16 + q15;
        if (d < DHD)
          attn[(size_t)(b * TSEQ + trow) * KPW + h * DHD + d] = f2bf(oacc[m][jd][r] * inv);
      }
    }
  }
}

// ---------------- launch ----------------

extern "C" void kernel_launch(void* const* d_in, const int* in_sizes, int n_in,
                              void* d_out, int out_size, void* d_ws, size_t ws_size,
                              hipStream_t stream) {
  const float* x   = (const float*)d_in[0];
  const float* mem = (const float*)d_in[1];
  const float* Wq  = (const float*)d_in[2];
  const float* Wk  = (const float*)d_in[3];
  const float* Wv  = (const float*)d_in[4];
  const float* Wp  = (const float*)d_in[5];
  const float* bp  = (const float*)d_in[6];
  float* out = (float*)d_out;

  char* ws = (char*)d_ws;
  const size_t SZ_XMB = (size_t)2 * NR * KPW * 2;  // 41,943,040
  const size_t SZ_WT  = (size_t)3 * HD * KPW * 2;  //  2,457,600 (q|v|k rows)
  const size_t SZ_WPT = (size_t)NP3 * KPW * 2;     //    983,040
  const size_t SZ_QB  = (size_t)NR * HD * 2;       // 20,971,520

  u16* xmb    = (u16*)(ws);            // [32768][640]; dead after projections
  u16* attn_o = (u16*)(ws);            // alias: [16384][640] padded
  u16* wt     = (u16*)(ws + SZ_XMB);
  u16* wp_t   = (u16*)(ws + SZ_XMB + SZ_WT);
  u16* q_buf  = (u16*)(ws + SZ_XMB + SZ_WT + SZ_WPT);       // q then vt contiguous
  u16* vt_buf = q_buf + (size_t)NR * HD;
  u16* k_buf  = (u16*)(ws + SZ_XMB + SZ_WT + SZ_WPT + 2 * SZ_QB);
  // total ws use: 41.9 + 2.5 + 1.0 + 62.9 MB ~= 108.3 MB

  (void)in_sizes; (void)n_in; (void)out_size; (void)ws_size;

  static bool s_attr = false;
  if (!s_attr) {
    (void)hipFuncSetAttribute((const void*)gemm8_kernel<4>,
                              hipFuncAttributeMaxDynamicSharedMemorySize, 65536);
    (void)hipFuncSetAttribute((const void*)gemm8_kernel<2>,
                              hipFuncAttributeMaxDynamicSharedMemorySize, 65536);
    s_attr = true;
  }

  // fused packs (2120 fat blocks)
  pack_all_kernel<<<PKA2 + PKB2 + PKC2, 256, 0, stream>>>(x, mem, Wq, Wk, Wv, Wp,
                                                          xmb, wt, wp_t);

  // all three projections in ONE launch; 1920 blocks, 2 blocks/CU
  gemm8_kernel<4><<<1920, 256, 65536, stream>>>(xmb, wt, q_buf, k_buf, nullptr);

  // attention: 1024 blocks x 256 threads, 4 blocks/CU, exactly co-resident
  attn_kernel<<<BB * HH * (TSEQ / 128), 256, 0, stream>>>(q_buf, k_buf, vt_buf, attn_o);

  // output projection + bias -> f32 out; 768 blocks, 2 blocks/CU
  gemm8_kernel<2><<<768, 256, 65536, stream>>>(attn_o, wp_t, out, nullptr, bp);
}

// Round 10
// 277.079 us; speedup vs baseline: 1.3140x; 1.3140x over previous
//
#include <hip/hip_runtime.h>
#include <hip/hip_bf16.h>

typedef unsigned short u16;
typedef __attribute__((ext_vector_type(4))) unsigned short u16x4;
typedef __attribute__((ext_vector_type(8))) unsigned short u16x8;
typedef __attribute__((ext_vector_type(8))) __bf16 bf16x8;
typedef __attribute__((ext_vector_type(4))) float f32x4;

#define BB 16
#define TSEQ 1024
#define CC 584          /* embed dim */
#define HH 8
#define DHD 73
#define NR (BB*TSEQ)    /* 16384 rows */
#define KPW 640         /* padded K: 10 x 64 K-tiles */
#define DP 80           /* padded head dim (73 -> 80 = 5x16) */
#define HD (HH*DP)      /* 640 */
#define NP3 768         /* padded N for final proj */
#define PPITCH 88
/* exp(s*584^-0.5) == exp2(s * CEXP); scores bounded -> no max subtraction */
#define CEXP 0.0596985934f

__device__ __forceinline__ u16 f2bf(float f) {
  __bf16 h = (__bf16)f;                 // native v_cvt, RNE
  return __builtin_bit_cast(u16, h);
}
__device__ __forceinline__ bf16x8 as_bf(u16x8 v) { return __builtin_bit_cast(bf16x8, v); }

/* async global->LDS, 16B/lane, LDS dst = wave-uniform base + lane*16 */
#define GLL16(g, l) __builtin_amdgcn_global_load_lds( \
    (const __attribute__((address_space(1))) void*)(g), \
    (__attribute__((address_space(3))) void*)(l), 16, 0, 0)

#define BARRIER() asm volatile("s_barrier" ::: "memory")
#define VMW8()    asm volatile("s_waitcnt vmcnt(8)" ::: "memory")
#define VMW0()    asm volatile("s_waitcnt vmcnt(0)" ::: "memory")

// ---------------- fused pack kernel (r7 config, kept) ----------------
#define PKA2 1280
#define PKB2 600
#define PKC2 240
__global__ void pack_all_kernel(const float* __restrict__ x, const float* __restrict__ mem,
                                const float* __restrict__ Wq, const float* __restrict__ Wk,
                                const float* __restrict__ Wv, const float* __restrict__ Wp,
                                u16* __restrict__ xmb, u16* __restrict__ wt,
                                u16* __restrict__ wpt) {
  const int bidx = blockIdx.x;
  const int tid = threadIdx.x;
  if (bidx < PKA2) {
    const int base = bidx * 2048 + tid;
#pragma unroll
    for (int e = 0; e < 8; e++) {
      int idx = base + e * 256;
      int row = idx / (KPW / 8);
      int c8  = (idx % (KPW / 8)) * 8;
      u16x8 o = {0, 0, 0, 0, 0, 0, 0, 0};
      if (c8 < CC) {
        const float* src = (row < NR) ? &x[(size_t)row * CC + c8]
                                      : &mem[(size_t)(row - NR) * CC + c8];
        f32x4 a = *(const f32x4*)src;
        f32x4 b = *(const f32x4*)(src + 4);
#pragma unroll
        for (int t = 0; t < 4; t++) { o[t] = f2bf(a[t]); o[4 + t] = f2bf(b[t]); }
      }
      *(u16x8*)&xmb[(size_t)row * KPW + c8] = o;
    }
  } else if (bidx < PKA2 + PKB2) {
    const int base = (bidx - PKA2) * 2048 + tid;
#pragma unroll
    for (int e = 0; e < 8; e++) {
      int idx = base + e * 256;
      int w   = idx / (HD * KPW);
      int rem = idx % (HD * KPW);
      int n = rem / KPW;
      int k = rem % KPW;
      int h = n / DP, d = n % DP;
      u16 val = 0;
      if (d < DHD && k < CC) {
        const float* W = (w == 0) ? Wq : ((w == 1) ? Wv : Wk);  // order: q, v, k
        val = f2bf(W[((size_t)h * CC + k) * DHD + d]);
      }
      wt[idx] = val;
    }
  } else {
    const int base = (bidx - PKA2 - PKB2) * 2048 + tid;
#pragma unroll
    for (int e = 0; e < 8; e++) {
      int idx = base + e * 256;
      int n = idx / KPW;
      int c = idx % KPW;
      u16 val = 0;
      if (n < CC && c < CC) val = f2bf(Wp[(size_t)c * CC + n]);
      wpt[idx] = val;
    }
  }
}

// ---------------- 128x128 GEMM, BK=64 dbuf, 2 blocks/CU (r8 proven) ----------------
// 256 threads = 4 waves (2M x 2N); wave owns 64x64 of C. LDS = 2 bufs x
// (A[128][64] + B[128][64]) bf16 = 64 KB exactly -> 2 blocks/CU: block
// prologue/epilogue/drain of one block overlaps steady-state of the other.
// Per K-tile t (buf=t&1): {16 ds_read_b128; 32 MFMA (compiler counted lgkm)};
// BARRIER; stage(t+2 -> buf t&1)[8 GLL16]; VMW8 retires tile t+1; BARRIER.
// T2 swizzle identical to r5-r7 (0 bank conflicts, verified).

__device__ __forceinline__ void rd4(bf16x8 (&v)[4][2], const u16* lds, int base,
                                    int sw0, int sw1) {
#pragma unroll
  for (int q = 0; q < 4; q++) {
    const int r = base + q * 1024;
    v[q][0] = as_bf(*(const u16x8*)&lds[r + sw0]);
    v[q][1] = as_bf(*(const u16x8*)&lds[r + sw1]);
  }
}
__device__ __forceinline__ void stg128(const u16* gA, const u16* gB, u16* ldst, int t) {
  const int lb = (t & 1) * 8192;
  const size_t ko = (size_t)t * 64;
#pragma unroll
  for (int u = 0; u < 4; u++)
    GLL16(gA + (size_t)(u * 32) * KPW + ko, ldst + lb + u * 2048);
#pragma unroll
  for (int u = 0; u < 4; u++)
    GLL16(gB + (size_t)(u * 32) * KPW + ko, ldst + 16384 + lb + u * 2048);
}

// MODE 4: A = xmb [32768][640]; bid<1280: x rows (nt<5 q; else v); bid>=1280:
//   mem rows, k cols 1280..1919. MODE 2: final proj + bias -> f32, col<584.
template <int MODE>
__global__ __launch_bounds__(256, 2) void gemm8_kernel(
    const u16* __restrict__ A, const u16* __restrict__ Bt,
    void* __restrict__ CoutV, void* __restrict__ CoutV2,
    const float* __restrict__ bias) {
  extern __shared__ u16 lds[];
  const int tid  = threadIdx.x;
  const int lane = tid & 63;
  const int q15  = lane & 15;
  const int quad = lane >> 4;
  const int wave = tid >> 6;      // 0..3
  const int wmi  = wave >> 1;     // 0..1
  const int wni  = wave & 1;      // 0..1

  // XCD-contiguous swizzle (grid % 8 == 0 for both modes)
  const int cpx = gridDim.x >> 3;
  const int bid = (blockIdx.x & 7) * cpx + (blockIdx.x >> 3);

  int m0, n0, npart;  // npart: 0=q 1=v 2=k (MODE4)
  if (MODE == 4) {
    if (bid < 1280) {
      m0 = (bid / 10) * 128; int nt = bid % 10;
      if (nt < 5) { n0 = nt * 128; npart = 0; }
      else        { n0 = 640 + (nt - 5) * 128; npart = 1; }
    } else {
      int b2 = bid - 1280;
      m0 = NR + (b2 / 5) * 128; n0 = 1280 + (b2 % 5) * 128; npart = 2;
    }
  } else {
    m0 = (bid / 6) * 128; n0 = (bid % 6) * 128; npart = 0;
  }

  // staging: thread t covers (row = t>>3 in a 32-row unit, chunk = t&7);
  // source chunk pre-swizzled so swizzled ds_read finds linear data (rule 21).
  const int tr   = tid >> 3;
  const int scol = ((tid & 7) ^ (tr & 7)) * 8;
  const u16* gA = &A[(size_t)(m0 + tr) * KPW + scol];
  const u16* gB = &Bt[(size_t)(n0 + tr) * KPW + scol];
  u16* ldst = &lds[tid * 8];

  // fragment-read swizzled 16B-slot offsets (frag row & 7 == q15 & 7)
  const int rb  = q15 & 7;
  const int sw0 = (quad ^ rb) * 8;
  const int sw1 = ((quad + 4) ^ rb) * 8;
  const int arow = (wmi * 64 + q15) * 64;
  const int brow = (wni * 64 + q15) * 64;

  f32x4 acc[4][4];
#pragma unroll
  for (int i = 0; i < 4; i++)
#pragma unroll
    for (int j = 0; j < 4; j++) acc[i][j] = (f32x4){0.f, 0.f, 0.f, 0.f};

  // prologue: tiles 0 and 1 staged; VMW8 -> tile 0 landed
  stg128(gA, gB, ldst, 0);
  stg128(gA, gB, ldst, 1);
  VMW8(); BARRIER();

#pragma unroll 1
  for (int t = 0; t < 10; ++t) {
    const int lb = (t & 1) * 8192;
    bf16x8 a[4][2], b[4][2];
    rd4(a, lds, lb + arow, sw0, sw1);
    rd4(b, lds, 16384 + lb + brow, sw0, sw1);
    __builtin_amdgcn_s_setprio(1);
#pragma unroll
    for (int mq = 0; mq < 4; mq++)
#pragma unroll
      for (int nq = 0; nq < 4; nq++) {
        f32x4 c = acc[mq][nq];
        c = __builtin_amdgcn_mfma_f32_16x16x32_bf16(a[mq][0], b[nq][0], c, 0, 0, 0);
        c = __builtin_amdgcn_mfma_f32_16x16x32_bf16(a[mq][1], b[nq][1], c, 0, 0, 0);
        acc[mq][nq] = c;
      }
    __builtin_amdgcn_s_setprio(0);
    if (t == 9) break;
    BARRIER();                       // all waves done reading buf(t)
    if (t < 8) { stg128(gA, gB, ldst, t + 2); VMW8(); }
    else       { VMW0(); }
    BARRIER();                       // tile t+1 visible
  }

  // epilogue: row = m0 + wmi*64 + mq*16 + quad*4 + r ; col = n0 + wni*64 + nq*16 + q15
  const int rowb = m0 + wmi * 64 + quad * 4;
  const int colb = n0 + wni * 64 + q15;
#pragma unroll
  for (int mq = 0; mq < 4; mq++)
#pragma unroll
    for (int nq = 0; nq < 4; nq++) {
      const f32x4 av = acc[mq][nq];
      const int row = rowb + mq * 16;
      const int col = colb + nq * 16;
      if (MODE == 4) {
        if (npart == 2) {          // k projection -> k_buf
          u16* Cout = (u16*)CoutV2;
          const int rk = row - NR;
          const int ck = col - 1280;
#pragma unroll
          for (int r = 0; r < 4; r++)
            Cout[(size_t)(rk + r) * HD + ck] = f2bf(av[r]);
        } else if (npart == 0) {   // q projection, row-major
          u16* Cout = (u16*)CoutV;
#pragma unroll
          for (int r = 0; r < 4; r++)
            Cout[(size_t)(row + r) * HD + col] = f2bf(av[r]);
        } else {                   // v projection, transposed store
          u16* Cout = (u16*)CoutV;
          const int vn = col - 640;
          const int bb = row >> 10;
          const int tl = row & 1023;
          u16x4 pk;
#pragma unroll
          for (int r = 0; r < 4; r++) pk[r] = f2bf(av[r]);
          *(u16x4*)&Cout[(size_t)(NR * HD) + ((size_t)(bb * HD + vn)) * TSEQ + tl] = pk;
        }
      } else {
        if (col < CC) {
          float* Cout = (float*)CoutV;
          const float bvv = bias[col];
#pragma unroll
          for (int r = 0; r < 4; r++)
            Cout[(size_t)(row + r) * CC + col] = av[r] + bvv;
        }
      }
    }
}

// ---------------- flash attention (r6/r8 exact config: QBLK=128, 256 thr) -------
// q,k: [B,T,640] bf16 ; vt: [B,640,T] bf16 ; out attn: [16384][640] bf16 padded.
__global__ __launch_bounds__(256, 3) void attn_kernel(
    const u16* __restrict__ qb, const u16* __restrict__ kb,
    const u16* __restrict__ vt, u16* __restrict__ attn) {
  __shared__ u16 smem[11264 + 64 * 88 + 80 * 72];
  u16* Pt = smem;                       // per-wave [32 q][pitch 88]
  u16* Ks = smem + 11264;               // [64 s][88 pitch] (80 cols used)
  u16* Vs = smem + 11264 + 64 * 88;     // [80 d][72 pitch] (64 s cols used)

  const int tid  = threadIdx.x;
  const int lane = tid & 63;
  const int wave = tid >> 6;
  const int q15  = lane & 15;
  const int quad = lane >> 4;
  const int bid  = blockIdx.x;
  const int loc  = bid >> 3;
  const int pair = (bid & 7) * 16 + (loc >> 3);
  const int b  = pair >> 3;
  const int h  = pair & 7;
  const int t0 = (loc & 7) * 128;
  const int wq0 = wave * 32;
  const bool w3 = (tid < 128);          // waves 0,1 handle the 3rd chunk

  // staging geometry: K = 64 rows x 10 chunks; V = 80 rows x 8 chunks (640 each)
  int krow[3], kc[3], vrow[3], vc[3];
#pragma unroll
  for (int p = 0; p < 3; p++) {
    int qk = tid + 256 * p;
    krow[p] = qk / 10; kc[p] = (qk % 10) * 8;
    vrow[p] = qk >> 3; vc[p] = (qk & 7) * 8;
  }
  const u16* kbase = &kb[(size_t)(b * TSEQ) * HD + h * DP];
  const u16* vbase = &vt[(size_t)(b * HD + h * DP) * TSEQ];

  // Q fragments direct from global (B-operand of S^T); tail quads>=2 zeroed
  bf16x8 aq[2][2], aqt[2];
  {
    const u16x8 z = {0, 0, 0, 0, 0, 0, 0, 0};
#pragma unroll
    for (int n = 0; n < 2; n++) {
      const size_t qrow = (size_t)(b * TSEQ + t0 + wq0 + n * 16 + q15) * HD + h * DP;
#pragma unroll
      for (int kcx = 0; kcx < 2; kcx++)
        aq[n][kcx] = as_bf(*(const u16x8*)&qb[qrow + kcx * 32 + quad * 8]);
      u16x8 tload = z;
      if (quad < 2) tload = *(const u16x8*)&qb[qrow + 64 + quad * 8];
      aqt[n] = as_bf(tload);
    }
  }

  // zero pad cols 584..639 of this block's output rows
  if (tid < 128) {
    const u16x8 z = {0, 0, 0, 0, 0, 0, 0, 0};
    size_t base = (size_t)(b * TSEQ + t0 + tid) * KPW + CC;
#pragma unroll
    for (int c = 0; c < (KPW - CC) / 8; c++) *(u16x8*)&attn[base + c * 8] = z;
  }

  float lsum[2] = {0.f, 0.f};
  f32x4 oacc[2][5];
#pragma unroll
  for (int m = 0; m < 2; m++)
#pragma unroll
    for (int jd = 0; jd < 5; jd++) oacc[m][jd] = (f32x4){0.f, 0.f, 0.f, 0.f};

  u16* Ptw = &Pt[wave * 32 * PPITCH];

  u16x8 kreg[3], vreg[3];
#pragma unroll
  for (int p = 0; p < 2; p++) {
    kreg[p] = *(const u16x8*)&kbase[(size_t)krow[p] * HD + kc[p]];
    vreg[p] = *(const u16x8*)&vbase[(size_t)vrow[p] * TSEQ + vc[p]];
  }
  if (w3) {
    kreg[2] = *(const u16x8*)&kbase[(size_t)krow[2] * HD + kc[2]];
    vreg[2] = *(const u16x8*)&vbase[(size_t)vrow[2] * TSEQ + vc[2]];
  }

  for (int si = 0; si < 16; ++si) {
#pragma unroll
    for (int p = 0; p < 2; p++) {
      *(u16x8*)&Ks[krow[p] * 88 + kc[p]] = kreg[p];
      *(u16x8*)&Vs[vrow[p] * 72 + vc[p]] = vreg[p];
    }
    if (w3) {
      *(u16x8*)&Ks[krow[2] * 88 + kc[2]] = kreg[2];
      *(u16x8*)&Vs[vrow[2] * 72 + vc[2]] = vreg[2];
    }
    __syncthreads();

    if (si < 15) {
      const int s1 = (si + 1) * 64;
#pragma unroll
      for (int p = 0; p < 2; p++) {
        kreg[p] = *(const u16x8*)&kbase[(size_t)(s1 + krow[p]) * HD + kc[p]];
        vreg[p] = *(const u16x8*)&vbase[(size_t)vrow[p] * TSEQ + s1 + vc[p]];
      }
      if (w3) {
        kreg[2] = *(const u16x8*)&kbase[(size_t)(s1 + krow[2]) * HD + kc[2]];
        vreg[2] = *(const u16x8*)&vbase[(size_t)vrow[2] * TSEQ + s1 + vc[2]];
      }
    }

    // S^T = K Q^T : rows = s (4 tiles), cols = q (2 tiles)
    f32x4 st[4][2];
#pragma unroll
    for (int mt = 0; mt < 4; mt++)
#pragma unroll
      for (int n = 0; n < 2; n++) st[mt][n] = (f32x4){0.f, 0.f, 0.f, 0.f};
#pragma unroll
    for (int kcx = 0; kcx < 2; kcx++) {
      bf16x8 ak[4];
#pragma unroll
      for (int mt = 0; mt < 4; mt++)
        ak[mt] = as_bf(*(const u16x8*)&Ks[(mt * 16 + q15) * 88 + kcx * 32 + quad * 8]);
#pragma unroll
      for (int mt = 0; mt < 4; mt++)
#pragma unroll
        for (int n = 0; n < 2; n++)
          st[mt][n] = __builtin_amdgcn_mfma_f32_16x16x32_bf16(ak[mt], aq[n][kcx], st[mt][n], 0, 0, 0);
    }
    {  // tail: k 64..79 (quads >=2 zeroed on both operands)
      const u16x8 z = {0, 0, 0, 0, 0, 0, 0, 0};
#pragma unroll
      for (int mt = 0; mt < 4; mt++) {
        u16x8 tl = z;
        if (quad < 2) tl = *(const u16x8*)&Ks[(mt * 16 + q15) * 88 + 64 + quad * 8];
        bf16x8 akt = as_bf(tl);
#pragma unroll
        for (int n = 0; n < 2; n++)
          st[mt][n] = __builtin_amdgcn_mfma_f32_16x16x32_bf16(akt, aqt[n], st[mt][n], 0, 0, 0);
      }
    }

    // p = exp2(s*CEXP); per-lane partial row sums; vectorized Pt store (wave-private)
#pragma unroll
    for (int mt = 0; mt < 4; mt++)
#pragma unroll
      for (int n = 0; n < 2; n++) {
        f32x4 pv;
#pragma unroll
        for (int r = 0; r < 4; r++) pv[r] = __builtin_amdgcn_exp2f(st[mt][n][r] * CEXP);
        lsum[n] += (pv[0] + pv[1]) + (pv[2] + pv[3]);
        u16x4 pk;
#pragma unroll
        for (int r = 0; r < 4; r++) pk[r] = f2bf(pv[r]);
        *(u16x4*)&Ptw[(n * 16 + q15) * PPITCH + mt * 16 + quad * 4] = pk;
      }

    // O += P V  (A = P from Pt, b128 reads; B = V^T rows)
#pragma unroll
    for (int kcx = 0; kcx < 2; kcx++) {
      bf16x8 ap[2];
#pragma unroll
      for (int m = 0; m < 2; m++)
        ap[m] = as_bf(*(const u16x8*)&Ptw[(m * 16 + q15) * PPITCH + kcx * 32 + quad * 8]);
#pragma unroll
      for (int jd = 0; jd < 5; jd++) {
        bf16x8 bv = as_bf(*(const u16x8*)&Vs[(jd * 16 + q15) * 72 + kcx * 32 + quad * 8]);
#pragma unroll
        for (int m = 0; m < 2; m++)
          oacc[m][jd] = __builtin_amdgcn_mfma_f32_16x16x32_bf16(ap[m], bv, oacc[m][jd], 0, 0, 0);
      }
    }
    __syncthreads();
  }

  float lr[2];
#pragma unroll
  for (int n = 0; n < 2; n++) {
    float s = lsum[n];
    s += __shfl_xor(s, 16);
    s += __shfl_xor(s, 32);
    lr[n] = s;
  }

#pragma unroll
  for (int m = 0; m < 2; m++) {
#pragma unroll
    for (int r = 0; r < 4; r++) {
      const float inv = 1.f / __shfl(lr[m], quad * 4 + r);
      const int trow = t0 + wq0 + m * 16 + quad * 4 + r;
#pragma unroll
      for (int jd = 0; jd < 5; jd++) {
        const int d = jd * 16 + q15;
        if (d < DHD)
          attn[(size_t)(b * TSEQ + trow) * KPW + h * DHD + d] = f2bf(oacc[m][jd][r] * inv);
      }
    }
  }
}

// ---------------- launch ----------------

extern "C" void kernel_launch(void* const* d_in, const int* in_sizes, int n_in,
                              void* d_out, int out_size, void* d_ws, size_t ws_size,
                              hipStream_t stream) {
  const float* x   = (const float*)d_in[0];
  const float* mem = (const float*)d_in[1];
  const float* Wq  = (const float*)d_in[2];
  const float* Wk  = (const float*)d_in[3];
  const float* Wv  = (const float*)d_in[4];
  const float* Wp  = (const float*)d_in[5];
  const float* bp  = (const float*)d_in[6];
  float* out = (float*)d_out;

  char* ws = (char*)d_ws;
  const size_t SZ_XMB = (size_t)2 * NR * KPW * 2;  // 41,943,040
  const size_t SZ_WT  = (size_t)3 * HD * KPW * 2;  //  2,457,600 (q|v|k rows)
  const size_t SZ_WPT = (size_t)NP3 * KPW * 2;     //    983,040
  const size_t SZ_QB  = (size_t)NR * HD * 2;       // 20,971,520

  u16* xmb    = (u16*)(ws);            // [32768][640]; dead after projections
  u16* attn_o = (u16*)(ws);            // alias: [16384][640] padded
  u16* wt     = (u16*)(ws + SZ_XMB);
  u16* wp_t   = (u16*)(ws + SZ_XMB + SZ_WT);
  u16* q_buf  = (u16*)(ws + SZ_XMB + SZ_WT + SZ_WPT);       // q then vt contiguous
  u16* vt_buf = q_buf + (size_t)NR * HD;
  u16* k_buf  = (u16*)(ws + SZ_XMB + SZ_WT + SZ_WPT + 2 * SZ_QB);
  // total ws use: 41.9 + 2.5 + 1.0 + 62.9 MB ~= 108.3 MB

  (void)in_sizes; (void)n_in; (void)out_size; (void)ws_size;

  static bool s_attr = false;
  if (!s_attr) {
    (void)hipFuncSetAttribute((const void*)gemm8_kernel<4>,
                              hipFuncAttributeMaxDynamicSharedMemorySize, 65536);
    (void)hipFuncSetAttribute((const void*)gemm8_kernel<2>,
                              hipFuncAttributeMaxDynamicSharedMemorySize, 65536);
    s_attr = true;
  }

  // fused packs (2120 fat blocks)
  pack_all_kernel<<<PKA2 + PKB2 + PKC2, 256, 0, stream>>>(x, mem, Wq, Wk, Wv, Wp,
                                                          xmb, wt, wp_t);

  // all three projections in ONE launch; 1920 blocks, 2 blocks/CU
  gemm8_kernel<4><<<1920, 256, 65536, stream>>>(xmb, wt, q_buf, k_buf, nullptr);

  // attention (r6/r8 config: 1024 blocks x 256 threads, 3 blocks/CU)
  attn_kernel<<<BB * HH * (TSEQ / 128), 256, 0, stream>>>(q_buf, k_buf, vt_buf, attn_o);

  // output projection + bias -> f32 out; 768 blocks, 2 blocks/CU
  gemm8_kernel<2><<<768, 256, 65536, stream>>>(attn_o, wp_t, out, nullptr, bp);
}